// Round 3
// baseline (564.449 us; speedup 1.0000x reference)
//
#include <hip/hip_runtime.h>
#include <stdint.h>

#define D_MODEL 2048
#define NUM_HEADS 16
#define D_K 128
#define BATCH 2
#define SEQ 2048
#define M_TOTAL (BATCH*SEQ)   // 4096 rows in all big GEMMs

typedef short  short8  __attribute__((ext_vector_type(8)));   // 8 bf16 raw bits = 4 VGPRs (MFMA A/B frag)
typedef short  short4v __attribute__((ext_vector_type(4)));
typedef short  short2v __attribute__((ext_vector_type(2)));
typedef float  float4v __attribute__((ext_vector_type(4)));   // MFMA C/D frag

// round-to-nearest-even fp32 -> bf16 raw bits (finite inputs only)
__device__ __forceinline__ short f2bf(float f) {
  union { float f; unsigned u; } v; v.f = f;
  unsigned r = (v.u + 0x7fffu + ((v.u >> 16) & 1u)) >> 16;
  return (short)r;
}

// ---------------------------------------------------------------------------
// fp32 -> bf16 conversion pass (memory-bound, ~6 GB/s-seconds of traffic total)
// ---------------------------------------------------------------------------
__global__ __launch_bounds__(256)
void cvt_f32_bf16(const float* __restrict__ in, short* __restrict__ outp, int n) {
  int stride = gridDim.x * blockDim.x * 4;
  for (int i = (blockIdx.x * blockDim.x + threadIdx.x) * 4; i < n; i += stride) {
    float4v v = *(const float4v*)(in + i);
    short4v s;
    s.x = f2bf(v.x); s.y = f2bf(v.y); s.z = f2bf(v.z); s.w = f2bf(v.w);
    *(short4v*)(outp + i) = s;
  }
}

// ---------------------------------------------------------------------------
// GEMM: C[m,n] = scale * sum_k A[m,k]*B[n,k]   (bf16 A/B, K-contiguous)
// 128x128 tile, BK=32, 4 waves in 2x2, each wave 64x64 (4x4 MFMA tiles).
// Register-staged short8 global loads -> ds_write_b128 (known-correct path).
// HEADS  -> store bf16 C at [B,H,S,dk] layout (n = h*128+d, m = b*2048+s)
// OUTF32 -> store fp32 C row-major [M, 2048]; else bf16 row-major
// ---------------------------------------------------------------------------
template<bool HEADS, bool OUTF32>
__global__ __launch_bounds__(256)
void gemm_bt(const short* __restrict__ A, const short* __restrict__ Bm,
             void* __restrict__ Cv, float scale) {
  __shared__ __align__(16) short As[128*32];
  __shared__ __align__(16) short Bs[128*32];

  const int tid  = threadIdx.x;
  const int w    = tid >> 6, lane = tid & 63;
  const int l15  = lane & 15, quad = lane >> 4;
  const int wm   = w & 1,  wn = w >> 1;
  const int mBase = blockIdx.y * 128, nBase = blockIdx.x * 128;
  const int K = D_MODEL;

  // each thread stages rows r and r+64, 16B chunk c, of both A and B tiles
  const int r = tid >> 2, c = tid & 3;
  const short* Ap = A  + (size_t)(mBase + r)*K + c*8;
  const short* Bp = Bm + (size_t)(nBase + r)*K + c*8;

  float4v acc[4][4] = {};

  for (int k0 = 0; k0 < K; k0 += 32) {
    short8 a0 = *(const short8*)(Ap + k0);
    short8 a1 = *(const short8*)(Ap + (size_t)64*K + k0);
    short8 b0 = *(const short8*)(Bp + k0);
    short8 b1 = *(const short8*)(Bp + (size_t)64*K + k0);

    __syncthreads();   // previous tile's LDS reads done before overwrite
    *(short8*)(As + r*32 + c*8)        = a0;
    *(short8*)(As + (r + 64)*32 + c*8) = a1;
    *(short8*)(Bs + r*32 + c*8)        = b0;
    *(short8*)(Bs + (r + 64)*32 + c*8) = b1;
    __syncthreads();

    short8 af[4], bf[4];
    #pragma unroll
    for (int i = 0; i < 4; ++i) {
      af[i] = *(const short8*)(As + (wm*64 + i*16 + l15)*32 + quad*8);
      bf[i] = *(const short8*)(Bs + (wn*64 + i*16 + l15)*32 + quad*8);
    }
    #pragma unroll
    for (int i = 0; i < 4; ++i)
      #pragma unroll
      for (int j = 0; j < 4; ++j)
        acc[i][j] = __builtin_amdgcn_mfma_f32_16x16x32_bf16(af[i], bf[j], acc[i][j], 0, 0, 0);
  }

  // epilogue; C/D layout: col = lane&15, row = quad*4 + reg
  #pragma unroll
  for (int i = 0; i < 4; ++i) {
    int m0 = mBase + wm*64 + i*16 + quad*4;
    #pragma unroll
    for (int j = 0; j < 4; ++j) {
      int n = nBase + wn*64 + j*16 + l15;
      #pragma unroll
      for (int rr2 = 0; rr2 < 4; ++rr2) {
        int m = m0 + rr2;
        float fv = acc[i][j][rr2] * scale;
        if (OUTF32) {
          ((float*)Cv)[(size_t)m * D_MODEL + n] = fv;
        } else if (HEADS) {
          int b = m >> 11, s = m & (SEQ-1);
          int h = n >> 7,  d = n & (D_K-1);
          ((short*)Cv)[(((size_t)(b*NUM_HEADS + h)*SEQ + s) << 7) + d] = f2bf(fv);
        } else {
          ((short*)Cv)[(size_t)m * D_MODEL + n] = f2bf(fv);
        }
      }
    }
  }
}

// ---------------------------------------------------------------------------
// Flash attention, one head-slice per block: 64 q-rows (4 waves x 16), 64-key tiles.
// Q pre-scaled by 1/sqrt(dk) in projection. bf16 in (ws), bf16 out (ws).
//   Ks[64][136]  K rows as-is (d contiguous)         -> QK^T B-operand
//   Vt[128][72]  V transposed (key contiguous)       -> PV   B-operand
//   Pl[w][16][72] per-wave P tile (key contiguous)   -> PV   A-operand
// ---------------------------------------------------------------------------
#define KS_LD 136
#define VT_LD 72
#define P_LD  72

__global__ __launch_bounds__(256)
void attn_fwd(const short* __restrict__ Q, const short* __restrict__ K,
              const short* __restrict__ V, short* __restrict__ O) {
  __shared__ __align__(16) short Ks[64*KS_LD];
  __shared__ __align__(16) short Vt[128*VT_LD];
  __shared__ __align__(16) short Pl[4][16*P_LD];

  const int tid  = threadIdx.x;
  const int w    = tid >> 6, lane = tid & 63;
  const int l15  = lane & 15, quad = lane >> 4;
  const int bh   = blockIdx.y;               // b*16 + h
  const int b    = bh >> 4, h = bh & 15;
  const int q0   = blockIdx.x * 64;
  const size_t hb = (size_t)bh * SEQ * D_K;
  const short* Qh = Q + hb;
  const short* Kh = K + hb;
  const short* Vh = V + hb;

  // Q fragments for this wave's 16 rows: A[m=l15][k=quad*8+j (+32c)]
  short8 qf[4];
  {
    const short* qr = Qh + (size_t)(q0 + w*16 + l15) * D_K;
    #pragma unroll
    for (int c = 0; c < 4; ++c) qf[c] = *(const short8*)(qr + c*32 + quad*8);
  }

  float4v Oa[8] = {};               // O accumulator, rows q=quad*4+r, cols d=dj*16+l15
  float mst[4], lst[4];
  #pragma unroll
  for (int r = 0; r < 4; ++r) { mst[r] = -1e30f; lst[r] = 0.f; }

  for (int kt = 0; kt < SEQ; kt += 64) {
    __syncthreads();
    // ---- stage K: 64 rows x 128, 16B per thread x4 ----
    {
      int rr = tid >> 4, ch = tid & 15;
      #pragma unroll
      for (int it = 0; it < 4; ++it) {
        int r = it*16 + rr;
        short8 kv = *(const short8*)(Kh + (size_t)(kt + r)*D_K + ch*8);
        *(short8*)(Ks + r*KS_LD + ch*8) = kv;
      }
      // ---- stage V transposed, packing key-pairs into dword writes ----
      int rp0 = tid & 15, ch2 = tid >> 4;
      #pragma unroll
      for (int it = 0; it < 2; ++it) {
        int r0 = (rp0 + it*16) * 2;
        short8 v0 = *(const short8*)(Vh + (size_t)(kt + r0    )*D_K + ch2*8);
        short8 v1 = *(const short8*)(Vh + (size_t)(kt + r0 + 1)*D_K + ch2*8);
        #pragma unroll
        for (int ee = 0; ee < 8; ++ee) {
          int e = (ee + 2*quad) & 7;              // rotate start to spread banks
          short2v pk; pk.x = v0[e]; pk.y = v1[e];
          *(short2v*)(Vt + (ch2*8 + e)*VT_LD + r0) = pk;
        }
      }
    }
    __syncthreads();

    // ---- QK^T: 16 q-rows x 64 keys ----
    float4v sc[4];
    #pragma unroll
    for (int kj = 0; kj < 4; ++kj) {
      float4v z = {};
      #pragma unroll
      for (int c = 0; c < 4; ++c) {
        short8 kf = *(const short8*)(Ks + (kj*16 + l15)*KS_LD + c*32 + quad*8);
        z = __builtin_amdgcn_mfma_f32_16x16x32_bf16(qf[c], kf, z, 0, 0, 0);
      }
      sc[kj] = z;
    }

    // ---- online softmax (rows q = quad*4 + r, stats uniform across quad's 16 lanes) ----
    float tm[4];
    #pragma unroll
    for (int r = 0; r < 4; ++r)
      tm[r] = fmaxf(fmaxf(sc[0][r], sc[1][r]), fmaxf(sc[2][r], sc[3][r]));
    #pragma unroll
    for (int off = 8; off >= 1; off >>= 1)
      #pragma unroll
      for (int r = 0; r < 4; ++r)
        tm[r] = fmaxf(tm[r], __shfl_xor(tm[r], off));

    float al[4], rs[4];
    #pragma unroll
    for (int r = 0; r < 4; ++r) {
      float mn = fmaxf(mst[r], tm[r]);
      al[r] = __expf(mst[r] - mn);
      mst[r] = mn;
      rs[r] = 0.f;
    }
    short pb[4][4];
    #pragma unroll
    for (int kj = 0; kj < 4; ++kj)
      #pragma unroll
      for (int r = 0; r < 4; ++r) {
        float p = __expf(sc[kj][r] - mst[r]);
        pb[kj][r] = f2bf(p);
        rs[r] += p;
      }
    #pragma unroll
    for (int off = 8; off >= 1; off >>= 1)
      #pragma unroll
      for (int r = 0; r < 4; ++r)
        rs[r] += __shfl_xor(rs[r], off);
    #pragma unroll
    for (int r = 0; r < 4; ++r) lst[r] = al[r]*lst[r] + rs[r];
    #pragma unroll
    for (int dj = 0; dj < 8; ++dj) {
      Oa[dj][0] *= al[0]; Oa[dj][1] *= al[1];
      Oa[dj][2] *= al[2]; Oa[dj][3] *= al[3];
    }

    // ---- P: C-layout -> LDS -> A-layout ----
    #pragma unroll
    for (int kj = 0; kj < 4; ++kj)
      #pragma unroll
      for (int r = 0; r < 4; ++r)
        Pl[w][(quad*4 + r)*P_LD + kj*16 + l15] = pb[kj][r];
    __syncthreads();   // make P writes unambiguously visible before A-frag reads

    // ---- PV: O[q][d] += P[q][key] * V[key][d] ----
    #pragma unroll
    for (int ks = 0; ks < 2; ++ks) {
      short8 ap = *(const short8*)(&Pl[w][l15*P_LD + ks*32 + quad*8]);
      #pragma unroll
      for (int dj = 0; dj < 8; ++dj) {
        short8 bv = *(const short8*)(Vt + (dj*16 + l15)*VT_LD + ks*32 + quad*8);
        Oa[dj] = __builtin_amdgcn_mfma_f32_16x16x32_bf16(ap, bv, Oa[dj], 0, 0, 0);
      }
    }
  }

  // ---- epilogue: normalize, store bf16 to [B,S,H*dk] ----
  float rl[4];
  #pragma unroll
  for (int r = 0; r < 4; ++r) rl[r] = 1.0f / lst[r];
  #pragma unroll
  for (int dj = 0; dj < 8; ++dj) {
    int d = dj*16 + l15;
    #pragma unroll
    for (int r = 0; r < 4; ++r) {
      int q = q0 + w*16 + quad*4 + r;
      O[(size_t)(b*SEQ + q)*D_MODEL + h*D_K + d] = f2bf(Oa[dj][r] * rl[r]);
    }
  }
}

// ---------------------------------------------------------------------------
extern "C" void kernel_launch(void* const* d_in, const int* in_sizes, int n_in,
                              void* d_out, int out_size, void* d_ws, size_t ws_size,
                              hipStream_t stream) {
  const float* x  = (const float*)d_in[0];
  const float* Wq = (const float*)d_in[1];
  const float* Wk = (const float*)d_in[2];
  const float* Wv = (const float*)d_in[3];
  const float* Wo = (const float*)d_in[4];
  float* out = (float*)d_out;

  const size_t NX = (size_t)M_TOTAL * D_MODEL;     // 8,388,608 (x / Q / K / V / AO elems)
  const size_t NW = (size_t)D_MODEL * D_MODEL;     // 4,194,304 (W elems)

  // ws layout (bf16 shorts). AO aliases xb: xb is dead after the projections.
  short* xb  = (short*)d_ws;       // [B,S,D]     (later reused as AO [B,S,D])
  short* Wqb = xb  + NX;
  short* Wkb = Wqb + NW;
  short* Wvb = Wkb + NW;
  short* Wob = Wvb + NW;
  short* Qw  = Wob + NW;           // [B,H,S,dk]
  short* Kw  = Qw  + NX;
  short* Vw  = Kw  + NX;
  short* AO  = xb;                 // alias
  // total: NX*2 + 4*NW*2 + 3*NX*2 = 96 MiB

  dim3 blk(256);
  dim3 gc(1024);
  cvt_f32_bf16<<<gc, blk, 0, stream>>>(x,  xb,  (int)NX);
  cvt_f32_bf16<<<gc, blk, 0, stream>>>(Wq, Wqb, (int)NW);
  cvt_f32_bf16<<<gc, blk, 0, stream>>>(Wk, Wkb, (int)NW);
  cvt_f32_bf16<<<gc, blk, 0, stream>>>(Wv, Wvb, (int)NW);
  cvt_f32_bf16<<<gc, blk, 0, stream>>>(Wo, Wob, (int)NW);

  dim3 g1(D_MODEL/128, M_TOTAL/128);            // 16 x 32
  const float qscale = 0.08838834764831845f;    // 1/sqrt(128)

  gemm_bt<true,  false><<<g1, blk, 0, stream>>>(xb, Wqb, Qw, qscale);
  gemm_bt<true,  false><<<g1, blk, 0, stream>>>(xb, Wkb, Kw, 1.0f);
  gemm_bt<true,  false><<<g1, blk, 0, stream>>>(xb, Wvb, Vw, 1.0f);

  dim3 g2(SEQ/64, BATCH*NUM_HEADS);             // 32 x 32
  attn_fwd<<<g2, blk, 0, stream>>>(Qw, Kw, Vw, AO);

  gemm_bt<false, true ><<<g1, blk, 0, stream>>>(AO, Wob, out, 1.0f);
}

// Round 4
// 479.876 us; speedup vs baseline: 1.1762x; 1.1762x over previous
//
#include <hip/hip_runtime.h>
#include <stdint.h>

#define D_MODEL 2048
#define NUM_HEADS 16
#define D_K 128
#define BATCH 2
#define SEQ 2048
#define M_TOTAL (BATCH*SEQ)   // 4096 rows in all big GEMMs

typedef short  short8  __attribute__((ext_vector_type(8)));   // 8 bf16 raw bits = 4 VGPRs (MFMA A/B frag)
typedef short  short4v __attribute__((ext_vector_type(4)));
typedef short  short2v __attribute__((ext_vector_type(2)));
typedef float  float4v __attribute__((ext_vector_type(4)));   // MFMA C/D frag

// round-to-nearest-even fp32 -> bf16 raw bits (finite inputs only)
__device__ __forceinline__ short f2bf(float f) {
  union { float f; unsigned u; } v; v.f = f;
  unsigned r = (v.u + 0x7fffu + ((v.u >> 16) & 1u)) >> 16;
  return (short)r;
}

// pack two fp32 -> two bf16 in one dword (round-half-up; bias < 2^-16 rel, fine for P in [0,1])
__device__ __forceinline__ unsigned pack2bf(float a, float b) {
  unsigned ua = __float_as_uint(a) + 0x8000u;
  unsigned ub = __float_as_uint(b) + 0x8000u;
  return (ua >> 16) | (ub & 0xffff0000u);
}

// async global->LDS, 16B per lane. LDS dest = wave-uniform base + lane*16.
__device__ __forceinline__ void async16(const void* g, void* l) {
  __builtin_amdgcn_global_load_lds((const __attribute__((address_space(1))) unsigned*)g,
                                   (__attribute__((address_space(3))) unsigned*)l,
                                   16, 0, 0);
}

// ---------------------------------------------------------------------------
// fp32 -> bf16 conversion pass (memory-bound)
// ---------------------------------------------------------------------------
__global__ __launch_bounds__(256)
void cvt_f32_bf16(const float* __restrict__ in, short* __restrict__ outp, int n) {
  int stride = gridDim.x * blockDim.x * 4;
  for (int i = (blockIdx.x * blockDim.x + threadIdx.x) * 4; i < n; i += stride) {
    float4v v = *(const float4v*)(in + i);
    short4v s;
    s.x = f2bf(v.x); s.y = f2bf(v.y); s.z = f2bf(v.z); s.w = f2bf(v.w);
    *(short4v*)(outp + i) = s;
  }
}

// ---------------------------------------------------------------------------
// GEMM: C[m,n] = scale * sum_k A[m,k]*B[n,k]   (bf16 A/B, K-contiguous)
// m97 structure: 128x128 tile, BK=32, global_load_lds width=16 staging.
// HEADS  -> store bf16 C at [B,H,S,dk] layout; OUTF32 -> fp32 row-major.
// ---------------------------------------------------------------------------
template<bool HEADS, bool OUTF32>
__global__ __launch_bounds__(256)
void gemm_bt(const short* __restrict__ A, const short* __restrict__ Bm,
             void* __restrict__ Cv, float scale) {
  __shared__ __align__(16) short As[128*32];
  __shared__ __align__(16) short Bs[128*32];

  const int tid  = threadIdx.x;
  const int w    = tid >> 6, lane = tid & 63;
  const int l15  = lane & 15, quad = lane >> 4;
  const int wm   = w & 1,  wn = w >> 1;
  const int mBase = blockIdx.y * 128, nBase = blockIdx.x * 128;
  const int K = D_MODEL;

  float4v acc[4][4] = {};

  for (int k0 = 0; k0 < K; k0 += 32) {
    __syncthreads();   // previous tile's LDS reads done before overwrite
    #pragma unroll
    for (int it = 0; it < 2; ++it) {
      int idx = it*256 + tid;
      int r = idx >> 2, c = idx & 3;                          // row 0..127, 16B-chunk 0..3
      char* abase = (char*)As + (size_t)(it*256 + w*64)*16;   // wave-uniform dest base
      char* bbase = (char*)Bs + (size_t)(it*256 + w*64)*16;
      async16(A  + (size_t)(mBase + r)*K + k0 + c*8, abase);
      async16(Bm + (size_t)(nBase + r)*K + k0 + c*8, bbase);
    }
    __syncthreads();   // compiler drains vmcnt before s_barrier

    short8 af[4], bf[4];
    #pragma unroll
    for (int i = 0; i < 4; ++i) {
      af[i] = *(const short8*)(As + (wm*64 + i*16 + l15)*32 + quad*8);
      bf[i] = *(const short8*)(Bs + (wn*64 + i*16 + l15)*32 + quad*8);
    }
    #pragma unroll
    for (int i = 0; i < 4; ++i)
      #pragma unroll
      for (int j = 0; j < 4; ++j)
        acc[i][j] = __builtin_amdgcn_mfma_f32_16x16x32_bf16(af[i], bf[j], acc[i][j], 0, 0, 0);
  }

  // epilogue; C/D layout: col = lane&15, row = quad*4 + reg
  #pragma unroll
  for (int i = 0; i < 4; ++i) {
    int m0 = mBase + wm*64 + i*16 + quad*4;
    #pragma unroll
    for (int j = 0; j < 4; ++j) {
      int n = nBase + wn*64 + j*16 + l15;
      #pragma unroll
      for (int rr2 = 0; rr2 < 4; ++rr2) {
        int m = m0 + rr2;
        float fv = acc[i][j][rr2] * scale;
        if (OUTF32) {
          ((float*)Cv)[(size_t)m * D_MODEL + n] = fv;
        } else if (HEADS) {
          int b = m >> 11, s = m & (SEQ-1);
          int h = n >> 7,  d = n & (D_K-1);
          ((short*)Cv)[(((size_t)(b*NUM_HEADS + h)*SEQ + s) << 7) + d] = f2bf(fv);
        } else {
          ((short*)Cv)[(size_t)m * D_MODEL + n] = f2bf(fv);
        }
      }
    }
  }
}

// ---------------------------------------------------------------------------
// Flash attention: 128 q-rows/block (4 waves x 32 as 2 subtiles of 16),
// 64-key tiles, transposed scores S^T = K*Q^T so softmax rows are per-lane.
// kf / Vt fragment reads shared across both q-subtiles (halves LDS reads/q).
//   Ks[64][136]   K rows natural (d contig)      -> QK^T A-operand
//   Vt[128][72]   V transposed (key contig)      -> PV   B-operand
//   Pl[w][s][16][72] per-wave P (key contig)     -> PV   A-operand
// LDS total 54272 B -> 2 blocks/CU; grid 512 = exactly 2/CU.
// ---------------------------------------------------------------------------
#define KS_LD 136
#define VT_LD 72
#define P_LD  72

__global__ __launch_bounds__(256)
void attn_fwd(const short* __restrict__ Q, const short* __restrict__ K,
              const short* __restrict__ V, short* __restrict__ O) {
  __shared__ __align__(16) short Ks[64*KS_LD];        // 17408 B
  __shared__ __align__(16) short Vt[128*VT_LD];       // 18432 B
  __shared__ __align__(16) short Pl[4][2][16*P_LD];   // 18432 B

  const int tid  = threadIdx.x;
  const int w    = tid >> 6, lane = tid & 63;
  const int l15  = lane & 15, quad = lane >> 4;
  const int bh   = blockIdx.y;               // b*16 + h
  const int b    = bh >> 4, h = bh & 15;
  const int q0   = blockIdx.x * 128;
  const size_t hb = (size_t)bh * SEQ * D_K;
  const short* Qh = Q + hb;
  const short* Kh = K + hb;
  const short* Vh = V + hb;

  // Q fragments (B-operand): lane n=l15 -> q row, k = c*32 + quad*8 + j
  short8 qf[2][4];
  #pragma unroll
  for (int s = 0; s < 2; ++s) {
    const short* qr = Qh + (size_t)(q0 + w*32 + s*16 + l15) * D_K;
    #pragma unroll
    for (int c = 0; c < 4; ++c) qf[s][c] = *(const short8*)(qr + c*32 + quad*8);
  }

  float4v Oa[2][8] = {};            // O: rows q = s*16 + quad*4 + r, cols d = dj*16 + l15
  float msta[2] = {-1e30f, -1e30f}; // softmax state per lane: q = s*16 + l15
  float lsta[2] = {0.f, 0.f};

  for (int kt = 0; kt < SEQ; kt += 64) {
    __syncthreads();
    // ---- stage K natural: 64 rows x 128 ----
    {
      int rr = tid >> 4, ch = tid & 15;
      #pragma unroll
      for (int it = 0; it < 4; ++it) {
        int r = it*16 + rr;
        short8 kv = *(const short8*)(Kh + (size_t)(kt + r)*D_K + ch*8);
        *(short8*)(Ks + r*KS_LD + ch*8) = kv;
      }
      // ---- stage V transposed, key-pairs packed into dword writes ----
      int rp0 = tid & 15, ch2 = tid >> 4;
      #pragma unroll
      for (int it = 0; it < 2; ++it) {
        int r0 = (rp0 + it*16) * 2;
        short8 v0 = *(const short8*)(Vh + (size_t)(kt + r0    )*D_K + ch2*8);
        short8 v1 = *(const short8*)(Vh + (size_t)(kt + r0 + 1)*D_K + ch2*8);
        #pragma unroll
        for (int ee = 0; ee < 8; ++ee) {
          int e = (ee + 2*quad) & 7;              // rotate start to spread banks
          short2v pk; pk.x = v0[e]; pk.y = v1[e];
          *(short2v*)(Vt + (ch2*8 + e)*VT_LD + r0) = pk;
        }
      }
    }
    __syncthreads();

    // ---- S^T = K*Q^T: 64 keys x 32 q; kf shared across subtiles ----
    // C layout: col = l15 = q(within subtile), row = quad*4 + r = key(within kj tile)
    float4v sc[2][4];
    #pragma unroll
    for (int kj = 0; kj < 4; ++kj) {
      float4v z0 = {}, z1 = {};
      #pragma unroll
      for (int c = 0; c < 4; ++c) {
        short8 kf = *(const short8*)(Ks + (kj*16 + l15)*KS_LD + c*32 + quad*8);
        z0 = __builtin_amdgcn_mfma_f32_16x16x32_bf16(kf, qf[0][c], z0, 0, 0, 0);
        z1 = __builtin_amdgcn_mfma_f32_16x16x32_bf16(kf, qf[1][c], z1, 0, 0, 0);
      }
      sc[0][kj] = z0; sc[1][kj] = z1;
    }

    // ---- online softmax per subtile; row q = s*16 + l15 lives in this lane ----
    float alv[2];
    #pragma unroll
    for (int s = 0; s < 2; ++s) {
      float mx = sc[s][0][0];
      #pragma unroll
      for (int kj = 0; kj < 4; ++kj)
        #pragma unroll
        for (int r = 0; r < 4; ++r)
          mx = fmaxf(mx, sc[s][kj][r]);
      mx = fmaxf(mx, __shfl_xor(mx, 16));
      mx = fmaxf(mx, __shfl_xor(mx, 32));
      float mn = fmaxf(msta[s], mx);
      alv[s] = __expf(msta[s] - mn);
      msta[s] = mn;

      float p[4][4], rsum = 0.f;
      #pragma unroll
      for (int kj = 0; kj < 4; ++kj)
        #pragma unroll
        for (int r = 0; r < 4; ++r) {
          p[kj][r] = __expf(sc[s][kj][r] - mn);
          rsum += p[kj][r];
        }
      rsum += __shfl_xor(rsum, 16);
      rsum += __shfl_xor(rsum, 32);
      lsta[s] = alv[s]*lsta[s] + rsum;

      // P write: row q=l15, keys kj*16+quad*4+{0..3} -> 8 dword writes
      #pragma unroll
      for (int kj = 0; kj < 4; ++kj) {
        *(unsigned*)(&Pl[w][s][l15*P_LD + kj*16 + quad*4    ]) = pack2bf(p[kj][0], p[kj][1]);
        *(unsigned*)(&Pl[w][s][l15*P_LD + kj*16 + quad*4 + 2]) = pack2bf(p[kj][2], p[kj][3]);
      }
    }

    // ---- rescale O accumulators (rows q = s*16 + quad*4 + r) ----
    #pragma unroll
    for (int s = 0; s < 2; ++s) {
      float a0 = __shfl(alv[s], quad*4 + 0);
      float a1 = __shfl(alv[s], quad*4 + 1);
      float a2 = __shfl(alv[s], quad*4 + 2);
      float a3 = __shfl(alv[s], quad*4 + 3);
      #pragma unroll
      for (int dj = 0; dj < 8; ++dj) {
        Oa[s][dj][0] *= a0; Oa[s][dj][1] *= a1;
        Oa[s][dj][2] *= a2; Oa[s][dj][3] *= a3;
      }
    }
    __syncthreads();   // P visibility (wave-internal; conservative)

    // ---- PV: bv shared across subtiles ----
    #pragma unroll
    for (int ks = 0; ks < 2; ++ks) {
      short8 ap0 = *(const short8*)(&Pl[w][0][l15*P_LD + ks*32 + quad*8]);
      short8 ap1 = *(const short8*)(&Pl[w][1][l15*P_LD + ks*32 + quad*8]);
      #pragma unroll
      for (int dj = 0; dj < 8; ++dj) {
        short8 bv = *(const short8*)(Vt + (dj*16 + l15)*VT_LD + ks*32 + quad*8);
        Oa[0][dj] = __builtin_amdgcn_mfma_f32_16x16x32_bf16(ap0, bv, Oa[0][dj], 0, 0, 0);
        Oa[1][dj] = __builtin_amdgcn_mfma_f32_16x16x32_bf16(ap1, bv, Oa[1][dj], 0, 0, 0);
      }
    }
  }

  // ---- epilogue: normalize, store bf16 to [B,S,H*dk] ----
  #pragma unroll
  for (int s = 0; s < 2; ++s) {
    float rl = 1.0f / lsta[s];
    float r0 = __shfl(rl, quad*4 + 0);
    float r1 = __shfl(rl, quad*4 + 1);
    float r2 = __shfl(rl, quad*4 + 2);
    float r3 = __shfl(rl, quad*4 + 3);
    float rv[4] = {r0, r1, r2, r3};
    #pragma unroll
    for (int dj = 0; dj < 8; ++dj) {
      int d = dj*16 + l15;
      #pragma unroll
      for (int r = 0; r < 4; ++r) {
        int q = q0 + w*32 + s*16 + quad*4 + r;
        O[(size_t)(b*SEQ + q)*D_MODEL + h*D_K + d] = f2bf(Oa[s][dj][r] * rv[r]);
      }
    }
  }
}

// ---------------------------------------------------------------------------
extern "C" void kernel_launch(void* const* d_in, const int* in_sizes, int n_in,
                              void* d_out, int out_size, void* d_ws, size_t ws_size,
                              hipStream_t stream) {
  const float* x  = (const float*)d_in[0];
  const float* Wq = (const float*)d_in[1];
  const float* Wk = (const float*)d_in[2];
  const float* Wv = (const float*)d_in[3];
  const float* Wo = (const float*)d_in[4];

  const size_t NX = (size_t)M_TOTAL * D_MODEL;     // 8,388,608
  const size_t NW = (size_t)D_MODEL * D_MODEL;     // 4,194,304

  // ws layout (bf16 shorts). AO aliases xb: xb is dead after the projections.
  short* xb  = (short*)d_ws;       // [B,S,D]   (later reused as AO)
  short* Wqb = xb  + NX;
  short* Wkb = Wqb + NW;
  short* Wvb = Wkb + NW;
  short* Wob = Wvb + NW;
  short* Qw  = Wob + NW;           // [B,H,S,dk]
  short* Kw  = Qw  + NX;
  short* Vw  = Kw  + NX;
  short* AO  = xb;                 // alias

  dim3 blk(256);
  dim3 gc(1024);
  cvt_f32_bf16<<<gc, blk, 0, stream>>>(x,  xb,  (int)NX);
  cvt_f32_bf16<<<gc, blk, 0, stream>>>(Wq, Wqb, (int)NW);
  cvt_f32_bf16<<<gc, blk, 0, stream>>>(Wk, Wkb, (int)NW);
  cvt_f32_bf16<<<gc, blk, 0, stream>>>(Wv, Wvb, (int)NW);
  cvt_f32_bf16<<<gc, blk, 0, stream>>>(Wo, Wob, (int)NW);

  dim3 g1(D_MODEL/128, M_TOTAL/128);            // 16 x 32
  const float qscale = 0.08838834764831845f;    // 1/sqrt(128)

  gemm_bt<true,  false><<<g1, blk, 0, stream>>>(xb, Wqb, Qw, qscale);
  gemm_bt<true,  false><<<g1, blk, 0, stream>>>(xb, Wkb, Kw, 1.0f);
  gemm_bt<true,  false><<<g1, blk, 0, stream>>>(xb, Wvb, Vw, 1.0f);

  dim3 g2(SEQ/128, BATCH*NUM_HEADS);            // 16 x 32 = 512 blocks
  attn_fwd<<<g2, blk, 0, stream>>>(Qw, Kw, Vw, AO);

  gemm_bt<false, true ><<<g1, blk, 0, stream>>>(AO, Wob, (float*)d_out, 1.0f);
}